// Round 5
// baseline (748.633 us; speedup 1.0000x reference)
//
#include <hip/hip_runtime.h>

// NeuralODE: x_{s+1} = x + (tanh(tanh(x W1 + b1) W2 + b2) W3 + b3) * dt_scale * DT
// BATCH=4096, STATE=64, HIDDEN=256, steps=200. Output [4096, 201, 64] fp32.
//
// R8 = R7 skeleton (verified 280us: weights-in-registers, operand-swapped MFMA,
// LDS-only barriers) with ONE structural change: TILE_M 16 -> 8, grid 256 -> 512
// so each CU hosts TWO independent blocks (4 waves/SIMD, VGPR 84 permits it).
// The two blocks barrier independently -> cross-block TLP hides the per-phase
// latency chains that phase-locked waves could not. MFMA cols 8-15 duplicate
// rows 0-7 (benign; stores gated to ln<8).

#define STATE_DIM 64
#define HIDDEN    256
#define ROWS      8       // batch rows per block
#define NBLK      512
#define XPITCH    68      // bf16 x pitch (shorts): mult of 4, non-pow2 banking
#define HPITCH    260     // bf16 h pitch (shorts): quads land on distinct banks

typedef short v8s __attribute__((ext_vector_type(8)));
typedef float v4f __attribute__((ext_vector_type(4)));

__device__ __forceinline__ unsigned short f2bf(float f) {
    return (unsigned short)((__float_as_uint(f) + 0x8000u) >> 16);  // round-half-up
}
__device__ __forceinline__ unsigned pk2bf(float a, float b) {
    return ((__float_as_uint(a) + 0x8000u) >> 16) |
           ((__float_as_uint(b) + 0x8000u) & 0xffff0000u);
}
__device__ __forceinline__ float fast_tanh(float x) {
    float e = __builtin_amdgcn_exp2f(x * 2.8853900817779268f);  // exp(2x)
    return 1.0f - 2.0f * __builtin_amdgcn_rcpf(e + 1.0f);
}
// LDS-only barrier (verified neutral vs __syncthreads in R7): global trajectory
// stores stay in flight across barriers; LDS writes drained via lgkmcnt.
__device__ __forceinline__ void sync_lds() {
    asm volatile("s_waitcnt lgkmcnt(0)" ::: "memory");
    __builtin_amdgcn_s_barrier();
    asm volatile("" ::: "memory");
}

// ---- prep: fp32 weights -> bf16, transposed to [N][K] ----
__global__ void prep_weights(const float* __restrict__ W1,
                             const float* __restrict__ W2,
                             const float* __restrict__ W3,
                             short* __restrict__ W1t,   // [256][64]
                             short* __restrict__ W2t,   // [256][256]
                             short* __restrict__ W3t) { // [64][256]
    int u = blockIdx.x * 256 + threadIdx.x;
    if (u < 65536) {                       // W2t[n][k] = W2[k][n]
        int n = u >> 8, k = u & 255;
        W2t[u] = (short)f2bf(W2[k * 256 + n]);
    }
    int v = u - 65536;
    if (v >= 0 && v < 16384) {             // W1t[n][k] = W1[k][n]
        int n = v >> 6, k = v & 63;
        W1t[v] = (short)f2bf(W1[k * 256 + n]);
    }
    int t = u - (65536 + 16384);
    if (t >= 0 && t < 16384) {             // W3t[n][k] = W3[k][n]
        int n = t >> 8, k = t & 255;
        W3t[t] = (short)f2bf(W3[k * 64 + n]);
    }
}

__global__ __launch_bounds__(512, 4)
void ode_kernel(const float* __restrict__ x0,
                const float* __restrict__ b1,
                const float* __restrict__ b2,
                const float* __restrict__ b3,
                const float* __restrict__ dt_scale,
                const int*   __restrict__ stepsp,
                const short* __restrict__ W1t,
                const short* __restrict__ W2t,
                const short* __restrict__ W3t,
                float* __restrict__ out) {
    __shared__ short xb [16 * XPITCH];    // bf16 x, B-operand source (rows 8-15 dup)
    __shared__ short h1b[16 * HPITCH];
    __shared__ short h2b[16 * HPITCH];

    const int tid  = threadIdx.x;
    const int w    = tid >> 6;        // wave 0..7
    const int lane = tid & 63;
    const int ln   = lane & 15;       // LDS row / MFMA col (8-15 duplicate 0-7)
    const int q    = lane >> 4;
    const int blk  = blockIdx.x;
    const int nsteps = *stepsp;
    const float scale = dt_scale[0] * 0.01f;
    const int n0 = 32 * w;            // this wave's 32 output features (L1/L2)
    const int brow = blk * ROWS + (ln & 7);   // global batch row (duplicated)
    const bool live = (ln < 8);               // lane owns a real row

    // ---- weight A-fragments in registers (A[m=ln][k=32ks+8q+j]) ----
    v8s w1f[2][2], w2f[2][8], w3f[8];
    #pragma unroll
    for (int t = 0; t < 2; t++)
        #pragma unroll
        for (int ks = 0; ks < 2; ks++)
            w1f[t][ks] = *(const v8s*)(W1t + (n0 + 16 * t + ln) * 64 + 32 * ks + 8 * q);
    #pragma unroll
    for (int t = 0; t < 2; t++)
        #pragma unroll
        for (int ks = 0; ks < 8; ks++)
            w2f[t][ks] = *(const v8s*)(W2t + (n0 + 16 * t + ln) * 256 + 32 * ks + 8 * q);
    if (w < 4) {
        #pragma unroll
        for (int ks = 0; ks < 8; ks++)
            w3f[ks] = *(const v8s*)(W3t + (16 * w + ln) * 256 + 32 * ks + 8 * q);
    }
    // ---- biases as per-lane float4 (C rows = feats 4q+i) ----
    v4f b1v[2], b2v[2], b3v = {0.f, 0.f, 0.f, 0.f};
    #pragma unroll
    for (int t = 0; t < 2; t++) {
        b1v[t] = *(const v4f*)(b1 + n0 + 16 * t + 4 * q);
        b2v[t] = *(const v4f*)(b2 + n0 + 16 * t + 4 * q);
    }
    if (w < 4) b3v = *(const v4f*)(b3 + 16 * w + 4 * q);

    // ---- x state in registers of waves 0-3: feats 16w+4q+i, batch row brow ----
    v4f x = {0.f, 0.f, 0.f, 0.f};
    unsigned tbase = 0;
    const int xw0 = ln * XPITCH + 16 * w + 4 * q;
    if (w < 4) {
        x = *(const v4f*)(x0 + (size_t)brow * STATE_DIM + 16 * w + 4 * q);
        uint2 p; p.x = pk2bf(x[0], x[1]); p.y = pk2bf(x[2], x[3]);
        *(uint2*)(xb + xw0) = p;       // rows 8-15 write duplicate values (benign)
        tbase = (unsigned)brow * (unsigned)((nsteps + 1) * STATE_DIM)
              + 16 * w + 4 * q;
        if (live) *(v4f*)(out + tbase) = x;    // trajectory sample 0
        tbase += STATE_DIM;
    }
    __syncthreads();   // pre-loop: full fence

    // ---- hoisted LDS indices ----
    int xrd[2], hrd[8];
    #pragma unroll
    for (int ks = 0; ks < 2; ks++) xrd[ks] = ln * XPITCH + 32 * ks + 8 * q;
    #pragma unroll
    for (int ks = 0; ks < 8; ks++) hrd[ks] = ln * HPITCH + 32 * ks + 8 * q;
    const int hw0 = ln * HPITCH + n0 + 4 * q;   // + 16*t for tile t

    for (int s = 0; s < nsteps; s++) {
        // ---- L1: h1 = tanh(x @ W1 + b1)  (A=W1 frags, B=xb) ----
        v8s xa0 = *(const v8s*)(xb + xrd[0]);
        v8s xa1 = *(const v8s*)(xb + xrd[1]);
        v4f a0 = b1v[0], a1 = b1v[1];
        a0 = __builtin_amdgcn_mfma_f32_16x16x32_bf16(w1f[0][0], xa0, a0, 0, 0, 0);
        a1 = __builtin_amdgcn_mfma_f32_16x16x32_bf16(w1f[1][0], xa0, a1, 0, 0, 0);
        a0 = __builtin_amdgcn_mfma_f32_16x16x32_bf16(w1f[0][1], xa1, a0, 0, 0, 0);
        a1 = __builtin_amdgcn_mfma_f32_16x16x32_bf16(w1f[1][1], xa1, a1, 0, 0, 0);
        {
            uint2 p0, p1;
            p0.x = pk2bf(fast_tanh(a0[0]), fast_tanh(a0[1]));
            p0.y = pk2bf(fast_tanh(a0[2]), fast_tanh(a0[3]));
            p1.x = pk2bf(fast_tanh(a1[0]), fast_tanh(a1[1]));
            p1.y = pk2bf(fast_tanh(a1[2]), fast_tanh(a1[3]));
            *(uint2*)(h1b + hw0)      = p0;
            *(uint2*)(h1b + hw0 + 16) = p1;
        }
        sync_lds();

        // ---- L2: h2 = tanh(h1 @ W2 + b2) ----
        v8s ha[8];
        #pragma unroll
        for (int ks = 0; ks < 8; ks++) ha[ks] = *(const v8s*)(h1b + hrd[ks]);
        a0 = b2v[0]; a1 = b2v[1];
        #pragma unroll
        for (int ks = 0; ks < 8; ks++) {
            a0 = __builtin_amdgcn_mfma_f32_16x16x32_bf16(w2f[0][ks], ha[ks], a0, 0, 0, 0);
            a1 = __builtin_amdgcn_mfma_f32_16x16x32_bf16(w2f[1][ks], ha[ks], a1, 0, 0, 0);
        }
        {
            uint2 p0, p1;
            p0.x = pk2bf(fast_tanh(a0[0]), fast_tanh(a0[1]));
            p0.y = pk2bf(fast_tanh(a0[2]), fast_tanh(a0[3]));
            p1.x = pk2bf(fast_tanh(a1[0]), fast_tanh(a1[1]));
            p1.y = pk2bf(fast_tanh(a1[2]), fast_tanh(a1[3]));
            *(uint2*)(h2b + hw0)      = p0;
            *(uint2*)(h2b + hw0 + 16) = p1;
        }
        sync_lds();

        // ---- L3 + Euler + trajectory store (waves 0-3; 4-7 idle) ----
        if (w < 4) {
            v8s hc[8];
            #pragma unroll
            for (int ks = 0; ks < 8; ks++) hc[ks] = *(const v8s*)(h2b + hrd[ks]);
            v4f a3 = b3v;
            #pragma unroll
            for (int ks = 0; ks < 8; ks++)
                a3 = __builtin_amdgcn_mfma_f32_16x16x32_bf16(w3f[ks], hc[ks], a3, 0, 0, 0);
            #pragma unroll
            for (int i = 0; i < 4; i++)
                x[i] = fmaf(a3[i], scale, x[i]);
            uint2 p; p.x = pk2bf(x[0], x[1]); p.y = pk2bf(x[2], x[3]);
            *(uint2*)(xb + xw0) = p;
            if (live) *(v4f*)(out + tbase) = x;   // trajectory sample s+1
            tbase += STATE_DIM;
        }
        sync_lds();
    }
}

extern "C" void kernel_launch(void* const* d_in, const int* in_sizes, int n_in,
                              void* d_out, int out_size, void* d_ws, size_t ws_size,
                              hipStream_t stream) {
    const float* x0 = (const float*)d_in[0];
    const float* W1 = (const float*)d_in[1];
    const float* b1 = (const float*)d_in[2];
    const float* W2 = (const float*)d_in[3];
    const float* b2 = (const float*)d_in[4];
    const float* W3 = (const float*)d_in[5];
    const float* b3 = (const float*)d_in[6];
    const float* dt = (const float*)d_in[7];
    const int* steps = (const int*)d_in[8];

    short* W1t = (short*)d_ws;            // 16384 bf16
    short* W2t = W1t + 64 * 256;          // 65536 bf16
    short* W3t = W2t + 256 * 256;         // 16384 bf16

    prep_weights<<<384, 256, 0, stream>>>(W1, W2, W3, W1t, W2t, W3t);
    ode_kernel<<<NBLK, 512, 0, stream>>>(x0, b1, b2, b3, dt, steps,
                                         W1t, W2t, W3t, (float*)d_out);
}

// Round 6
// 521.508 us; speedup vs baseline: 1.4355x; 1.4355x over previous
//
#include <hip/hip_runtime.h>

// NeuralODE: x_{s+1} = x + (tanh(tanh(x W1 + b1) W2 + b2) W3 + b3) * dt_scale * DT
// BATCH=4096, STATE=64, HIDDEN=256, steps=200. Output [4096, 201, 64] fp32.
//
// R9: 4 waves x 64 features (was 8 waves x 32). Same rows/CU, ~2/3 the LDS
// traffic: each wave's 8 B-fragment reads now feed 4 accumulator chains
// (w2f[4][8] = 192 VGPRs of resident weights; 1 wave/SIMD so register budget
// is legal). L3 becomes symmetric: every wave owns 16 output feats + x-state.
// R8 showed step time scales with per-CU pipe work, not wave count -> reduce
// the dominant uncounted pipe (LDS). Skeleton else identical to verified R7.

#define STATE_DIM 64
#define HIDDEN    256
#define TILE_M    16
#define NBLK      256
#define XPITCH    68      // bf16 x pitch (shorts): mult of 4, non-pow2 banking
#define HPITCH    260     // bf16 h pitch (shorts): quads land on distinct banks

typedef short v8s __attribute__((ext_vector_type(8)));
typedef float v4f __attribute__((ext_vector_type(4)));

__device__ __forceinline__ unsigned short f2bf(float f) {
    return (unsigned short)((__float_as_uint(f) + 0x8000u) >> 16);  // round-half-up
}
__device__ __forceinline__ unsigned pk2bf(float a, float b) {
    return ((__float_as_uint(a) + 0x8000u) >> 16) |
           ((__float_as_uint(b) + 0x8000u) & 0xffff0000u);
}
__device__ __forceinline__ float fast_tanh(float x) {
    float e = __builtin_amdgcn_exp2f(x * 2.8853900817779268f);  // exp(2x)
    return 1.0f - 2.0f * __builtin_amdgcn_rcpf(e + 1.0f);
}
// LDS-only barrier (verified neutral vs __syncthreads in R7): trajectory
// stores stay in flight across barriers; LDS writes drained via lgkmcnt.
__device__ __forceinline__ void sync_lds() {
    asm volatile("s_waitcnt lgkmcnt(0)" ::: "memory");
    __builtin_amdgcn_s_barrier();
    asm volatile("" ::: "memory");
}

// ---- prep: fp32 weights -> bf16, transposed to [N][K] ----
__global__ void prep_weights(const float* __restrict__ W1,
                             const float* __restrict__ W2,
                             const float* __restrict__ W3,
                             short* __restrict__ W1t,   // [256][64]
                             short* __restrict__ W2t,   // [256][256]
                             short* __restrict__ W3t) { // [64][256]
    int u = blockIdx.x * 256 + threadIdx.x;
    if (u < 65536) {                       // W2t[n][k] = W2[k][n]
        int n = u >> 8, k = u & 255;
        W2t[u] = (short)f2bf(W2[k * 256 + n]);
    }
    int v = u - 65536;
    if (v >= 0 && v < 16384) {             // W1t[n][k] = W1[k][n]
        int n = v >> 6, k = v & 63;
        W1t[v] = (short)f2bf(W1[k * 256 + n]);
    }
    int t = u - (65536 + 16384);
    if (t >= 0 && t < 16384) {             // W3t[n][k] = W3[k][n]
        int n = t >> 8, k = t & 255;
        W3t[t] = (short)f2bf(W3[k * 64 + n]);
    }
}

__global__ __launch_bounds__(256, 1)
void ode_kernel(const float* __restrict__ x0,
                const float* __restrict__ b1,
                const float* __restrict__ b2,
                const float* __restrict__ b3,
                const float* __restrict__ dt_scale,
                const int*   __restrict__ stepsp,
                const short* __restrict__ W1t,
                const short* __restrict__ W2t,
                const short* __restrict__ W3t,
                float* __restrict__ out) {
    __shared__ short xb [TILE_M * XPITCH];    // bf16 x, B-operand source
    __shared__ short h1b[TILE_M * HPITCH];
    __shared__ short h2b[TILE_M * HPITCH];

    const int tid  = threadIdx.x;
    const int w    = tid >> 6;        // wave 0..3
    const int lane = tid & 63;
    const int ln   = lane & 15;       // batch row (B col / C col)
    const int q    = lane >> 4;
    const int blk  = blockIdx.x;
    const int nsteps = *stepsp;
    const float scale = dt_scale[0] * 0.01f;
    const int n0 = 64 * w;            // this wave's 64 hidden features (L1/L2)
    const int m0 = 16 * w;            // this wave's 16 state features (L3/x)

    // ---- weight A-fragments in registers (A[m=ln][k=32ks+8q+j]) ----
    v8s w1f[4][2], w2f[4][8], w3f[8];
    #pragma unroll
    for (int t = 0; t < 4; t++)
        #pragma unroll
        for (int ks = 0; ks < 2; ks++)
            w1f[t][ks] = *(const v8s*)(W1t + (n0 + 16 * t + ln) * 64 + 32 * ks + 8 * q);
    #pragma unroll
    for (int t = 0; t < 4; t++)
        #pragma unroll
        for (int ks = 0; ks < 8; ks++)
            w2f[t][ks] = *(const v8s*)(W2t + (n0 + 16 * t + ln) * 256 + 32 * ks + 8 * q);
    #pragma unroll
    for (int ks = 0; ks < 8; ks++)
        w3f[ks] = *(const v8s*)(W3t + (m0 + ln) * 256 + 32 * ks + 8 * q);

    // ---- biases as per-lane float4 (C rows = feats 4q+i) ----
    v4f b1v[4], b2v[4], b3v;
    #pragma unroll
    for (int t = 0; t < 4; t++) {
        b1v[t] = *(const v4f*)(b1 + n0 + 16 * t + 4 * q);
        b2v[t] = *(const v4f*)(b2 + n0 + 16 * t + 4 * q);
    }
    b3v = *(const v4f*)(b3 + m0 + 4 * q);

    // ---- x state: every wave owns feats m0+4q+i of batch row ln ----
    v4f x;
    const int xw0 = ln * XPITCH + m0 + 4 * q;
    x = *(const v4f*)(x0 + (size_t)(blk * TILE_M + ln) * STATE_DIM + m0 + 4 * q);
    {
        uint2 p; p.x = pk2bf(x[0], x[1]); p.y = pk2bf(x[2], x[3]);
        *(uint2*)(xb + xw0) = p;
    }
    unsigned tbase = (unsigned)(blk * TILE_M + ln) * (unsigned)((nsteps + 1) * STATE_DIM)
                   + m0 + 4 * q;
    *(v4f*)(out + tbase) = x;          // trajectory sample 0
    tbase += STATE_DIM;
    __syncthreads();   // pre-loop: full fence

    // ---- hoisted LDS indices ----
    int xrd[2], hrd[8];
    #pragma unroll
    for (int ks = 0; ks < 2; ks++) xrd[ks] = ln * XPITCH + 32 * ks + 8 * q;
    #pragma unroll
    for (int ks = 0; ks < 8; ks++) hrd[ks] = ln * HPITCH + 32 * ks + 8 * q;
    const int hw0 = ln * HPITCH + n0 + 4 * q;   // + 16*t for tile t

    for (int s = 0; s < nsteps; s++) {
        // ---- L1: h1 = tanh(x @ W1 + b1)  (A=W1 frags, B=xb; 4 tiles/wave) ----
        v8s xa0 = *(const v8s*)(xb + xrd[0]);
        v8s xa1 = *(const v8s*)(xb + xrd[1]);
        v4f a[4];
        #pragma unroll
        for (int t = 0; t < 4; t++) {
            a[t] = b1v[t];
            a[t] = __builtin_amdgcn_mfma_f32_16x16x32_bf16(w1f[t][0], xa0, a[t], 0, 0, 0);
            a[t] = __builtin_amdgcn_mfma_f32_16x16x32_bf16(w1f[t][1], xa1, a[t], 0, 0, 0);
        }
        #pragma unroll
        for (int t = 0; t < 4; t++) {
            uint2 p;
            p.x = pk2bf(fast_tanh(a[t][0]), fast_tanh(a[t][1]));
            p.y = pk2bf(fast_tanh(a[t][2]), fast_tanh(a[t][3]));
            *(uint2*)(h1b + hw0 + 16 * t) = p;
        }
        sync_lds();

        // ---- L2: h2 = tanh(h1 @ W2 + b2) -- 4 independent chains, shared B ----
        v8s ha[8];
        #pragma unroll
        for (int ks = 0; ks < 8; ks++) ha[ks] = *(const v8s*)(h1b + hrd[ks]);
        #pragma unroll
        for (int t = 0; t < 4; t++) a[t] = b2v[t];
        #pragma unroll
        for (int ks = 0; ks < 8; ks++)
            #pragma unroll
            for (int t = 0; t < 4; t++)
                a[t] = __builtin_amdgcn_mfma_f32_16x16x32_bf16(w2f[t][ks], ha[ks], a[t], 0, 0, 0);
        #pragma unroll
        for (int t = 0; t < 4; t++) {
            uint2 p;
            p.x = pk2bf(fast_tanh(a[t][0]), fast_tanh(a[t][1]));
            p.y = pk2bf(fast_tanh(a[t][2]), fast_tanh(a[t][3]));
            *(uint2*)(h2b + hw0 + 16 * t) = p;
        }
        sync_lds();

        // ---- L3 + Euler + trajectory store (ALL waves, 1 tile each) ----
        {
            v8s hc[8];
            #pragma unroll
            for (int ks = 0; ks < 8; ks++) hc[ks] = *(const v8s*)(h2b + hrd[ks]);
            v4f a3 = b3v;
            v4f c3 = {0.f, 0.f, 0.f, 0.f};
            #pragma unroll
            for (int ks = 0; ks < 4; ks++) {
                a3 = __builtin_amdgcn_mfma_f32_16x16x32_bf16(w3f[ks],     hc[ks],     a3, 0, 0, 0);
                c3 = __builtin_amdgcn_mfma_f32_16x16x32_bf16(w3f[ks + 4], hc[ks + 4], c3, 0, 0, 0);
            }
            #pragma unroll
            for (int i = 0; i < 4; i++)
                x[i] = fmaf(a3[i] + c3[i], scale, x[i]);
            uint2 p; p.x = pk2bf(x[0], x[1]); p.y = pk2bf(x[2], x[3]);
            *(uint2*)(xb + xw0) = p;
            *(v4f*)(out + tbase) = x;      // trajectory sample s+1 (floats free)
            tbase += STATE_DIM;
        }
        sync_lds();
    }
}

extern "C" void kernel_launch(void* const* d_in, const int* in_sizes, int n_in,
                              void* d_out, int out_size, void* d_ws, size_t ws_size,
                              hipStream_t stream) {
    const float* x0 = (const float*)d_in[0];
    const float* W1 = (const float*)d_in[1];
    const float* b1 = (const float*)d_in[2];
    const float* W2 = (const float*)d_in[3];
    const float* b2 = (const float*)d_in[4];
    const float* W3 = (const float*)d_in[5];
    const float* b3 = (const float*)d_in[6];
    const float* dt = (const float*)d_in[7];
    const int* steps = (const int*)d_in[8];

    short* W1t = (short*)d_ws;            // 16384 bf16
    short* W2t = W1t + 64 * 256;          // 65536 bf16
    short* W3t = W2t + 256 * 256;         // 16384 bf16

    prep_weights<<<384, 256, 0, stream>>>(W1, W2, W3, W1t, W2t, W3t);
    ode_kernel<<<NBLK, 256, 0, stream>>>(x0, b1, b2, b3, dt, steps,
                                         W1t, W2t, W3t, (float*)d_out);
}

// Round 7
// 433.470 us; speedup vs baseline: 1.7271x; 1.2031x over previous
//
#include <hip/hip_runtime.h>

// NeuralODE: x_{s+1} = x + (tanh(tanh(x W1 + b1) W2 + b2) W3 + b3) * dt_scale * DT
// BATCH=4096, STATE=64, HIDDEN=256, steps=200. Output [4096, 201, 64] fp32.
//
// R10 = R7 skeleton (verified 280us) + ONE change: weight fragments and biases
// are PINNED into VGPRs via asm "+v" definition points. Diagnosis: every prior
// version declared 112-192 VGPRs worth of weight fragments but the compiler
// allocated only 84-144 -> it was re-loading fragments from L2 inside the step
// loop (invisible in FETCH_SIZE; explains the unattributed ~40% stall, R1's 3x
// collapse, R8's linear scaling, R9's regression). Pinning forces residency;
// budget ~210 VGPR fits the 256 cap at 2 waves/SIMD.

#define STATE_DIM 64
#define HIDDEN    256
#define TILE_M    16
#define NBLK      256
#define XPITCH    68      // bf16 x pitch (shorts): mult of 4, non-pow2 banking
#define HPITCH    260     // bf16 h pitch (shorts): quads land on distinct banks

typedef short v8s __attribute__((ext_vector_type(8)));
typedef float v4f __attribute__((ext_vector_type(4)));

#define PIN(v) asm volatile("" : "+v"(v))

__device__ __forceinline__ unsigned short f2bf(float f) {
    return (unsigned short)((__float_as_uint(f) + 0x8000u) >> 16);  // round-half-up
}
__device__ __forceinline__ unsigned pk2bf(float a, float b) {
    return ((__float_as_uint(a) + 0x8000u) >> 16) |
           ((__float_as_uint(b) + 0x8000u) & 0xffff0000u);
}
__device__ __forceinline__ float fast_tanh(float x) {
    float e = __builtin_amdgcn_exp2f(x * 2.8853900817779268f);  // exp(2x)
    return 1.0f - 2.0f * __builtin_amdgcn_rcpf(e + 1.0f);
}
// LDS-only barrier (verified neutral vs __syncthreads in R7): trajectory
// stores stay in flight across barriers; LDS writes drained via lgkmcnt.
__device__ __forceinline__ void sync_lds() {
    asm volatile("s_waitcnt lgkmcnt(0)" ::: "memory");
    __builtin_amdgcn_s_barrier();
    asm volatile("" ::: "memory");
}

// ---- prep: fp32 weights -> bf16, transposed to [N][K] ----
__global__ void prep_weights(const float* __restrict__ W1,
                             const float* __restrict__ W2,
                             const float* __restrict__ W3,
                             short* __restrict__ W1t,   // [256][64]
                             short* __restrict__ W2t,   // [256][256]
                             short* __restrict__ W3t) { // [64][256]
    int u = blockIdx.x * 256 + threadIdx.x;
    if (u < 65536) {                       // W2t[n][k] = W2[k][n]
        int n = u >> 8, k = u & 255;
        W2t[u] = (short)f2bf(W2[k * 256 + n]);
    }
    int v = u - 65536;
    if (v >= 0 && v < 16384) {             // W1t[n][k] = W1[k][n]
        int n = v >> 6, k = v & 63;
        W1t[v] = (short)f2bf(W1[k * 256 + n]);
    }
    int t = u - (65536 + 16384);
    if (t >= 0 && t < 16384) {             // W3t[n][k] = W3[k][n]
        int n = t >> 8, k = t & 255;
        W3t[t] = (short)f2bf(W3[k * 64 + n]);
    }
}

__global__ __launch_bounds__(512, 2)
void ode_kernel(const float* __restrict__ x0,
                const float* __restrict__ b1,
                const float* __restrict__ b2,
                const float* __restrict__ b3,
                const float* __restrict__ dt_scale,
                const int*   __restrict__ stepsp,
                const short* __restrict__ W1t,
                const short* __restrict__ W2t,
                const short* __restrict__ W3t,
                float* __restrict__ out) {
    __shared__ short xb [TILE_M * XPITCH];    // bf16 x, B-operand source
    __shared__ short h1b[TILE_M * HPITCH];
    __shared__ short h2b[TILE_M * HPITCH];

    const int tid  = threadIdx.x;
    const int w    = tid >> 6;        // wave 0..7
    const int lane = tid & 63;
    const int ln   = lane & 15;       // batch row (B col / C col)
    const int q    = lane >> 4;
    const int blk  = blockIdx.x;
    const int nsteps = *stepsp;
    const float scale = dt_scale[0] * 0.01f;
    const int n0 = 32 * w;            // this wave's 32 output features (L1/L2)

    // ---- weight A-fragments in registers (A[m=ln][k=32ks+8q+j]) ----
    v8s w1f[2][2], w2f[2][8], w3f[8];
    #pragma unroll
    for (int t = 0; t < 2; t++)
        #pragma unroll
        for (int ks = 0; ks < 2; ks++)
            w1f[t][ks] = *(const v8s*)(W1t + (n0 + 16 * t + ln) * 64 + 32 * ks + 8 * q);
    #pragma unroll
    for (int t = 0; t < 2; t++)
        #pragma unroll
        for (int ks = 0; ks < 8; ks++)
            w2f[t][ks] = *(const v8s*)(W2t + (n0 + 16 * t + ln) * 256 + 32 * ks + 8 * q);
    #pragma unroll
    for (int ks = 0; ks < 8; ks++) w3f[ks] = (v8s)0;
    if (w < 4) {
        #pragma unroll
        for (int ks = 0; ks < 8; ks++)
            w3f[ks] = *(const v8s*)(W3t + (16 * w + ln) * 256 + 32 * ks + 8 * q);
    }
    // ---- biases as per-lane float4 (C rows = feats 4q+i) ----
    v4f b1v[2], b2v[2], b3v = {0.f, 0.f, 0.f, 0.f};
    #pragma unroll
    for (int t = 0; t < 2; t++) {
        b1v[t] = *(const v4f*)(b1 + n0 + 16 * t + 4 * q);
        b2v[t] = *(const v4f*)(b2 + n0 + 16 * t + 4 * q);
    }
    if (w < 4) b3v = *(const v4f*)(b3 + 16 * w + 4 * q);

    // ---- PIN all loop-invariant fragments into VGPRs (defeat remat/reload) ----
    #pragma unroll
    for (int t = 0; t < 2; t++) {
        PIN(w1f[t][0]); PIN(w1f[t][1]);
        #pragma unroll
        for (int ks = 0; ks < 8; ks++) PIN(w2f[t][ks]);
        PIN(b1v[t]); PIN(b2v[t]);
    }
    #pragma unroll
    for (int ks = 0; ks < 8; ks++) PIN(w3f[ks]);
    PIN(b3v);

    // ---- x state in registers of waves 0-3: feats 16w+4q+i, batch ln ----
    v4f x = {0.f, 0.f, 0.f, 0.f};
    unsigned tbase = 0;
    const int xw0 = ln * XPITCH + 16 * w + 4 * q;
    if (w < 4) {
        x = *(const v4f*)(x0 + (size_t)(blk * TILE_M + ln) * STATE_DIM + 16 * w + 4 * q);
        uint2 p; p.x = pk2bf(x[0], x[1]); p.y = pk2bf(x[2], x[3]);
        *(uint2*)(xb + xw0) = p;
        tbase = (unsigned)(blk * TILE_M + ln) * (unsigned)((nsteps + 1) * STATE_DIM)
              + 16 * w + 4 * q;
        *(v4f*)(out + tbase) = x;          // trajectory sample 0
        tbase += STATE_DIM;
    }
    __syncthreads();   // pre-loop: full fence (x0 loads + sample-0 store)

    // ---- hoisted LDS indices ----
    int xrd[2], hrd[8];
    #pragma unroll
    for (int ks = 0; ks < 2; ks++) xrd[ks] = ln * XPITCH + 32 * ks + 8 * q;
    #pragma unroll
    for (int ks = 0; ks < 8; ks++) hrd[ks] = ln * HPITCH + 32 * ks + 8 * q;
    const int hw0 = ln * HPITCH + n0 + 4 * q;   // + 16*t for tile t

    for (int s = 0; s < nsteps; s++) {
        // ---- L1: h1 = tanh(x @ W1 + b1)  (A=W1 frags, B=xb) ----
        v8s xa0 = *(const v8s*)(xb + xrd[0]);
        v8s xa1 = *(const v8s*)(xb + xrd[1]);
        v4f a0 = b1v[0], a1 = b1v[1];
        a0 = __builtin_amdgcn_mfma_f32_16x16x32_bf16(w1f[0][0], xa0, a0, 0, 0, 0);
        a1 = __builtin_amdgcn_mfma_f32_16x16x32_bf16(w1f[1][0], xa0, a1, 0, 0, 0);
        a0 = __builtin_amdgcn_mfma_f32_16x16x32_bf16(w1f[0][1], xa1, a0, 0, 0, 0);
        a1 = __builtin_amdgcn_mfma_f32_16x16x32_bf16(w1f[1][1], xa1, a1, 0, 0, 0);
        {
            uint2 p0, p1;
            p0.x = pk2bf(fast_tanh(a0[0]), fast_tanh(a0[1]));
            p0.y = pk2bf(fast_tanh(a0[2]), fast_tanh(a0[3]));
            p1.x = pk2bf(fast_tanh(a1[0]), fast_tanh(a1[1]));
            p1.y = pk2bf(fast_tanh(a1[2]), fast_tanh(a1[3]));
            *(uint2*)(h1b + hw0)      = p0;
            *(uint2*)(h1b + hw0 + 16) = p1;
        }
        sync_lds();

        // ---- L2: h2 = tanh(h1 @ W2 + b2) ----
        v8s ha[8];
        #pragma unroll
        for (int ks = 0; ks < 8; ks++) ha[ks] = *(const v8s*)(h1b + hrd[ks]);
        a0 = b2v[0]; a1 = b2v[1];
        #pragma unroll
        for (int ks = 0; ks < 8; ks++) {
            a0 = __builtin_amdgcn_mfma_f32_16x16x32_bf16(w2f[0][ks], ha[ks], a0, 0, 0, 0);
            a1 = __builtin_amdgcn_mfma_f32_16x16x32_bf16(w2f[1][ks], ha[ks], a1, 0, 0, 0);
        }
        {
            uint2 p0, p1;
            p0.x = pk2bf(fast_tanh(a0[0]), fast_tanh(a0[1]));
            p0.y = pk2bf(fast_tanh(a0[2]), fast_tanh(a0[3]));
            p1.x = pk2bf(fast_tanh(a1[0]), fast_tanh(a1[1]));
            p1.y = pk2bf(fast_tanh(a1[2]), fast_tanh(a1[3]));
            *(uint2*)(h2b + hw0)      = p0;
            *(uint2*)(h2b + hw0 + 16) = p1;
        }
        sync_lds();

        // ---- L3 + Euler + trajectory store (waves 0-3; 4-7 idle) ----
        if (w < 4) {
            v8s hc[8];
            #pragma unroll
            for (int ks = 0; ks < 8; ks++) hc[ks] = *(const v8s*)(h2b + hrd[ks]);
            v4f a3 = b3v;
            #pragma unroll
            for (int ks = 0; ks < 8; ks++)
                a3 = __builtin_amdgcn_mfma_f32_16x16x32_bf16(w3f[ks], hc[ks], a3, 0, 0, 0);
            #pragma unroll
            for (int i = 0; i < 4; i++)
                x[i] = fmaf(a3[i], scale, x[i]);
            uint2 p; p.x = pk2bf(x[0], x[1]); p.y = pk2bf(x[2], x[3]);
            *(uint2*)(xb + xw0) = p;
            *(v4f*)(out + tbase) = x;      // trajectory sample s+1 (floats free)
            tbase += STATE_DIM;
        }
        sync_lds();
    }
}

extern "C" void kernel_launch(void* const* d_in, const int* in_sizes, int n_in,
                              void* d_out, int out_size, void* d_ws, size_t ws_size,
                              hipStream_t stream) {
    const float* x0 = (const float*)d_in[0];
    const float* W1 = (const float*)d_in[1];
    const float* b1 = (const float*)d_in[2];
    const float* W2 = (const float*)d_in[3];
    const float* b2 = (const float*)d_in[4];
    const float* W3 = (const float*)d_in[5];
    const float* b3 = (const float*)d_in[6];
    const float* dt = (const float*)d_in[7];
    const int* steps = (const int*)d_in[8];

    short* W1t = (short*)d_ws;            // 16384 bf16
    short* W2t = W1t + 64 * 256;          // 65536 bf16
    short* W3t = W2t + 256 * 256;         // 16384 bf16

    prep_weights<<<384, 256, 0, stream>>>(W1, W2, W3, W1t, W2t, W3t);
    ode_kernel<<<NBLK, 512, 0, stream>>>(x0, b1, b2, b3, dt, steps,
                                         W1t, W2t, W3t, (float*)d_out);
}

// Round 8
// 416.651 us; speedup vs baseline: 1.7968x; 1.0404x over previous
//
#include <hip/hip_runtime.h>

// NeuralODE: x_{s+1} = x + (tanh(tanh(x W1 + b1) W2 + b2) W3 + b3) * dt_scale * DT
// BATCH=4096, STATE=64, HIDDEN=256, steps=200. Output [4096, 201, 64] fp32.
//
// R11 = verified R7 skeleton (281us: operand-swapped MFMA, weights resident,
// LDS-only barriers) + VALU trims:
//   (1) tanh input scale 2/ln2 folded into W1/W2/b1/b2 (prep-side) -> fast_tanh
//       loses its v_mul (16/wave/step);
//   (2) bf16 pair pack via v_perm_b32 (3 ops vs 5), guarded fallback.
// Model: step = serial sum of pipe work (R8 scaling proof). LDS+MFMA at floor;
// VALU is the one reducible term.

#define STATE_DIM 64
#define HIDDEN    256
#define TILE_M    16
#define NBLK      256
#define XPITCH    68      // bf16 x pitch (shorts): mult of 4, non-pow2 banking
#define HPITCH    260     // bf16 h pitch (shorts): quads land on distinct banks
#define LOG2E2    2.8853900817779268f   // 2/ln2

typedef short v8s __attribute__((ext_vector_type(8)));
typedef float v4f __attribute__((ext_vector_type(4)));

__device__ __forceinline__ unsigned short f2bf(float f) {
    return (unsigned short)((__float_as_uint(f) + 0x8000u) >> 16);  // round-half-up
}
__device__ __forceinline__ unsigned pk2bf(float a, float b) {
#if __has_builtin(__builtin_amdgcn_perm)
    // {hi16(b+r), hi16(a+r)} in one v_perm_b32
    return __builtin_amdgcn_perm(__float_as_uint(b) + 0x8000u,
                                 __float_as_uint(a) + 0x8000u,
                                 0x07060302u);
#else
    return ((__float_as_uint(a) + 0x8000u) >> 16) |
           ((__float_as_uint(b) + 0x8000u) & 0xffff0000u);
#endif
}
// input a is PRE-SCALED by 2/ln2 (folded into weights): tanh = 1 - 2/(2^a + 1)
__device__ __forceinline__ float fast_tanh_pre(float a) {
    float e = __builtin_amdgcn_exp2f(a);
    return fmaf(-2.0f, __builtin_amdgcn_rcpf(e + 1.0f), 1.0f);
}
// LDS-only barrier (verified neutral vs __syncthreads in R7): trajectory
// stores stay in flight across barriers; LDS writes drained via lgkmcnt.
__device__ __forceinline__ void sync_lds() {
    asm volatile("s_waitcnt lgkmcnt(0)" ::: "memory");
    __builtin_amdgcn_s_barrier();
    asm volatile("" ::: "memory");
}

// ---- prep: fp32 weights -> bf16, transposed to [N][K]; W1/W2 pre-scaled ----
__global__ void prep_weights(const float* __restrict__ W1,
                             const float* __restrict__ W2,
                             const float* __restrict__ W3,
                             short* __restrict__ W1t,   // [256][64]  * 2/ln2
                             short* __restrict__ W2t,   // [256][256] * 2/ln2
                             short* __restrict__ W3t) { // [64][256]
    int u = blockIdx.x * 256 + threadIdx.x;
    if (u < 65536) {                       // W2t[n][k] = s * W2[k][n]
        int n = u >> 8, k = u & 255;
        W2t[u] = (short)f2bf(W2[k * 256 + n] * LOG2E2);
    }
    int v = u - 65536;
    if (v >= 0 && v < 16384) {             // W1t[n][k] = s * W1[k][n]
        int n = v >> 6, k = v & 63;
        W1t[v] = (short)f2bf(W1[k * 256 + n] * LOG2E2);
    }
    int t = u - (65536 + 16384);
    if (t >= 0 && t < 16384) {             // W3t[n][k] = W3[k][n]  (unscaled)
        int n = t >> 8, k = t & 255;
        W3t[t] = (short)f2bf(W3[k * 64 + n]);
    }
}

__global__ __launch_bounds__(512, 2)
void ode_kernel(const float* __restrict__ x0,
                const float* __restrict__ b1,
                const float* __restrict__ b2,
                const float* __restrict__ b3,
                const float* __restrict__ dt_scale,
                const int*   __restrict__ stepsp,
                const short* __restrict__ W1t,
                const short* __restrict__ W2t,
                const short* __restrict__ W3t,
                float* __restrict__ out) {
    __shared__ short xb [TILE_M * XPITCH];    // bf16 x, B-operand source
    __shared__ short h1b[TILE_M * HPITCH];
    __shared__ short h2b[TILE_M * HPITCH];

    const int tid  = threadIdx.x;
    const int w    = tid >> 6;        // wave 0..7
    const int lane = tid & 63;
    const int ln   = lane & 15;       // batch row (B col / C col)
    const int q    = lane >> 4;
    const int blk  = blockIdx.x;
    const int nsteps = *stepsp;
    const float scale = dt_scale[0] * 0.01f;
    const int n0 = 32 * w;            // this wave's 32 output features (L1/L2)

    // ---- weight A-fragments in registers (A[m=ln][k=32ks+8q+j]) ----
    v8s w1f[2][2], w2f[2][8], w3f[8];
    #pragma unroll
    for (int t = 0; t < 2; t++)
        #pragma unroll
        for (int ks = 0; ks < 2; ks++)
            w1f[t][ks] = *(const v8s*)(W1t + (n0 + 16 * t + ln) * 64 + 32 * ks + 8 * q);
    #pragma unroll
    for (int t = 0; t < 2; t++)
        #pragma unroll
        for (int ks = 0; ks < 8; ks++)
            w2f[t][ks] = *(const v8s*)(W2t + (n0 + 16 * t + ln) * 256 + 32 * ks + 8 * q);
    if (w < 4) {
        #pragma unroll
        for (int ks = 0; ks < 8; ks++)
            w3f[ks] = *(const v8s*)(W3t + (16 * w + ln) * 256 + 32 * ks + 8 * q);
    }
    // ---- biases as per-lane float4 (C rows = feats 4q+i); b1/b2 pre-scaled ----
    v4f b1v[2], b2v[2], b3v = {0.f, 0.f, 0.f, 0.f};
    #pragma unroll
    for (int t = 0; t < 2; t++) {
        b1v[t] = *(const v4f*)(b1 + n0 + 16 * t + 4 * q) * LOG2E2;
        b2v[t] = *(const v4f*)(b2 + n0 + 16 * t + 4 * q) * LOG2E2;
    }
    if (w < 4) b3v = *(const v4f*)(b3 + 16 * w + 4 * q);

    // ---- x state in registers of waves 0-3: feats 16w+4q+i, batch ln ----
    v4f x = {0.f, 0.f, 0.f, 0.f};
    unsigned tbase = 0;
    const int xw0 = ln * XPITCH + 16 * w + 4 * q;
    if (w < 4) {
        x = *(const v4f*)(x0 + (size_t)(blk * TILE_M + ln) * STATE_DIM + 16 * w + 4 * q);
        uint2 p; p.x = pk2bf(x[0], x[1]); p.y = pk2bf(x[2], x[3]);
        *(uint2*)(xb + xw0) = p;
        tbase = (unsigned)(blk * TILE_M + ln) * (unsigned)((nsteps + 1) * STATE_DIM)
              + 16 * w + 4 * q;
        *(v4f*)(out + tbase) = x;          // trajectory sample 0
        tbase += STATE_DIM;
    }
    __syncthreads();   // pre-loop: full fence (x0 loads + sample-0 store)

    // ---- hoisted LDS indices ----
    int xrd[2], hrd[8];
    #pragma unroll
    for (int ks = 0; ks < 2; ks++) xrd[ks] = ln * XPITCH + 32 * ks + 8 * q;
    #pragma unroll
    for (int ks = 0; ks < 8; ks++) hrd[ks] = ln * HPITCH + 32 * ks + 8 * q;
    const int hw0 = ln * HPITCH + n0 + 4 * q;   // + 16*t for tile t

    for (int s = 0; s < nsteps; s++) {
        // ---- L1: h1 = tanh(x @ W1s + b1s)  (A=W1 frags, B=xb) ----
        v8s xa0 = *(const v8s*)(xb + xrd[0]);
        v8s xa1 = *(const v8s*)(xb + xrd[1]);
        v4f a0 = b1v[0], a1 = b1v[1];
        a0 = __builtin_amdgcn_mfma_f32_16x16x32_bf16(w1f[0][0], xa0, a0, 0, 0, 0);
        a1 = __builtin_amdgcn_mfma_f32_16x16x32_bf16(w1f[1][0], xa0, a1, 0, 0, 0);
        a0 = __builtin_amdgcn_mfma_f32_16x16x32_bf16(w1f[0][1], xa1, a0, 0, 0, 0);
        a1 = __builtin_amdgcn_mfma_f32_16x16x32_bf16(w1f[1][1], xa1, a1, 0, 0, 0);
        {
            uint2 p0, p1;
            p0.x = pk2bf(fast_tanh_pre(a0[0]), fast_tanh_pre(a0[1]));
            p0.y = pk2bf(fast_tanh_pre(a0[2]), fast_tanh_pre(a0[3]));
            p1.x = pk2bf(fast_tanh_pre(a1[0]), fast_tanh_pre(a1[1]));
            p1.y = pk2bf(fast_tanh_pre(a1[2]), fast_tanh_pre(a1[3]));
            *(uint2*)(h1b + hw0)      = p0;
            *(uint2*)(h1b + hw0 + 16) = p1;
        }
        sync_lds();

        // ---- L2: h2 = tanh(h1 @ W2s + b2s) ----
        v8s ha[8];
        #pragma unroll
        for (int ks = 0; ks < 8; ks++) ha[ks] = *(const v8s*)(h1b + hrd[ks]);
        a0 = b2v[0]; a1 = b2v[1];
        #pragma unroll
        for (int ks = 0; ks < 8; ks++) {
            a0 = __builtin_amdgcn_mfma_f32_16x16x32_bf16(w2f[0][ks], ha[ks], a0, 0, 0, 0);
            a1 = __builtin_amdgcn_mfma_f32_16x16x32_bf16(w2f[1][ks], ha[ks], a1, 0, 0, 0);
        }
        {
            uint2 p0, p1;
            p0.x = pk2bf(fast_tanh_pre(a0[0]), fast_tanh_pre(a0[1]));
            p0.y = pk2bf(fast_tanh_pre(a0[2]), fast_tanh_pre(a0[3]));
            p1.x = pk2bf(fast_tanh_pre(a1[0]), fast_tanh_pre(a1[1]));
            p1.y = pk2bf(fast_tanh_pre(a1[2]), fast_tanh_pre(a1[3]));
            *(uint2*)(h2b + hw0)      = p0;
            *(uint2*)(h2b + hw0 + 16) = p1;
        }
        sync_lds();

        // ---- L3 + Euler + trajectory store (waves 0-3; 4-7 idle) ----
        if (w < 4) {
            v8s hc[8];
            #pragma unroll
            for (int ks = 0; ks < 8; ks++) hc[ks] = *(const v8s*)(h2b + hrd[ks]);
            v4f a3 = b3v;
            #pragma unroll
            for (int ks = 0; ks < 8; ks++)
                a3 = __builtin_amdgcn_mfma_f32_16x16x32_bf16(w3f[ks], hc[ks], a3, 0, 0, 0);
            #pragma unroll
            for (int i = 0; i < 4; i++)
                x[i] = fmaf(a3[i], scale, x[i]);
            uint2 p; p.x = pk2bf(x[0], x[1]); p.y = pk2bf(x[2], x[3]);
            *(uint2*)(xb + xw0) = p;
            *(v4f*)(out + tbase) = x;      // trajectory sample s+1 (floats free)
            tbase += STATE_DIM;
        }
        sync_lds();
    }
}

extern "C" void kernel_launch(void* const* d_in, const int* in_sizes, int n_in,
                              void* d_out, int out_size, void* d_ws, size_t ws_size,
                              hipStream_t stream) {
    const float* x0 = (const float*)d_in[0];
    const float* W1 = (const float*)d_in[1];
    const float* b1 = (const float*)d_in[2];
    const float* W2 = (const float*)d_in[3];
    const float* b2 = (const float*)d_in[4];
    const float* W3 = (const float*)d_in[5];
    const float* b3 = (const float*)d_in[6];
    const float* dt = (const float*)d_in[7];
    const int* steps = (const int*)d_in[8];

    short* W1t = (short*)d_ws;            // 16384 bf16 (scaled)
    short* W2t = W1t + 64 * 256;          // 65536 bf16 (scaled)
    short* W3t = W2t + 256 * 256;         // 16384 bf16

    prep_weights<<<384, 256, 0, stream>>>(W1, W2, W3, W1t, W2t, W3t);
    ode_kernel<<<NBLK, 512, 0, stream>>>(x0, b1, b2, b3, dt, steps,
                                         W1t, W2t, W3t, (float*)d_out);
}

// Round 9
// 363.159 us; speedup vs baseline: 2.0615x; 1.1473x over previous
//
#include <hip/hip_runtime.h>

// NeuralODE: x_{s+1} = x + (tanh(tanh(x W1 + b1) W2 + b2) W3 + b3) * dt_scale * DT
// BATCH=4096, STATE=64, HIDDEN=256, steps=200. Output [4096, 201, 64] fp32.
//
// R12 = R11 skeleton (267us) with L2/L3 moved to MX-scaled fp8 K=128 MFMA:
//   - W2/W3 quantized e4m3 x64 (prep), HW scale_A = 2^-6  -> net x1
//   - h1/h2 stored fp8 x16 (fold into tanh: 16 - 32*rcp), scale_B = 2^-4
//   - L2: 4 mfma_scale_16x16x128 (was 16 bf16), L3: 2 (was 8)
//   - LDS reads 112 -> 64 ds_read_b128/step/CU; h tiles fp8 [16][272B]
// L1 / x-state path stays bf16 (precision). Serial-pipe-sum model (R8/R11
// verified): LDS 1560->950, MFMA 830->500, VALU ~same => wall ~196us.

#define STATE_DIM 64
#define HIDDEN    256
#define TILE_M    16
#define NBLK      256
#define XPITCH    68      // bf16 x pitch (shorts): mult of 4, non-pow2 banking
#define HQPITCH   272     // fp8 h pitch (BYTES): 16B-aligned, 17*16 -> conflict-free
#define LOG2E2    2.8853900817779268f   // 2/ln2
#define SCALE_A   0x79797979            // e8m0 2^-6 replicated (weights stored x64)
#define SCALE_B   0x7B7B7B7B            // e8m0 2^-4 replicated (acts stored x16)

typedef short v8s __attribute__((ext_vector_type(8)));
typedef int   v8i __attribute__((ext_vector_type(8)));
typedef float v4f __attribute__((ext_vector_type(4)));

__device__ __forceinline__ unsigned short f2bf(float f) {
    return (unsigned short)((__float_as_uint(f) + 0x8000u) >> 16);  // round-half-up
}
__device__ __forceinline__ unsigned char f2fp8(float f) {
    int r = __builtin_amdgcn_cvt_pk_fp8_f32(f, 0.f, 0, false);
    return (unsigned char)(r & 0xff);
}
__device__ __forceinline__ unsigned pk2bf(float a, float b) {
#if __has_builtin(__builtin_amdgcn_perm)
    return __builtin_amdgcn_perm(__float_as_uint(b) + 0x8000u,
                                 __float_as_uint(a) + 0x8000u,
                                 0x07060302u);
#else
    return ((__float_as_uint(a) + 0x8000u) >> 16) |
           ((__float_as_uint(b) + 0x8000u) & 0xffff0000u);
#endif
}
// input a PRE-SCALED by 2/ln2 (folded into weights): returns 16*tanh
__device__ __forceinline__ float fast_tanh16(float a) {
    float e = __builtin_amdgcn_exp2f(a);
    return fmaf(-32.0f, __builtin_amdgcn_rcpf(e + 1.0f), 16.0f);
}
// LDS-only barrier (verified neutral vs __syncthreads in R7)
__device__ __forceinline__ void sync_lds() {
    asm volatile("s_waitcnt lgkmcnt(0)" ::: "memory");
    __builtin_amdgcn_s_barrier();
    asm volatile("" ::: "memory");
}

// ---- prep: W1 -> bf16 [256][64] x 2/ln2; W2 -> fp8 [256][256] x 2/ln2 x64;
//            W3 -> fp8 [64][256] x64. All transposed to [N][K]. ----
__global__ void prep_weights(const float* __restrict__ W1,
                             const float* __restrict__ W2,
                             const float* __restrict__ W3,
                             short* __restrict__ W1t,
                             unsigned char* __restrict__ W2q,
                             unsigned char* __restrict__ W3q) {
    int u = blockIdx.x * 256 + threadIdx.x;
    if (u < 65536) {                       // W2q[n][k] = fp8(s64 * W2[k][n])
        int n = u >> 8, k = u & 255;
        W2q[u] = f2fp8(W2[k * 256 + n] * (LOG2E2 * 64.0f));
    }
    int v = u - 65536;
    if (v >= 0 && v < 16384) {             // W1t[n][k] = bf16(s * W1[k][n])
        int n = v >> 6, k = v & 63;
        W1t[v] = (short)f2bf(W1[k * 256 + n] * LOG2E2);
    }
    int t = u - (65536 + 16384);
    if (t >= 0 && t < 16384) {             // W3q[n][k] = fp8(64 * W3[k][n])
        int n = t >> 8, k = t & 255;
        W3q[t] = f2fp8(W3[k * 64 + n] * 64.0f);
    }
}

__global__ __launch_bounds__(512, 2)
void ode_kernel(const float* __restrict__ x0,
                const float* __restrict__ b1,
                const float* __restrict__ b2,
                const float* __restrict__ b3,
                const float* __restrict__ dt_scale,
                const int*   __restrict__ stepsp,
                const short* __restrict__ W1t,
                const unsigned char* __restrict__ W2q,
                const unsigned char* __restrict__ W3q,
                float* __restrict__ out) {
    __shared__ short xb [TILE_M * XPITCH];                              // bf16 x
    __shared__ __attribute__((aligned(16))) unsigned char h1b[TILE_M * HQPITCH];
    __shared__ __attribute__((aligned(16))) unsigned char h2b[TILE_M * HQPITCH];

    const int tid  = threadIdx.x;
    const int w    = tid >> 6;        // wave 0..7
    const int lane = tid & 63;
    const int ln   = lane & 15;       // batch row (B col / C col)
    const int q    = lane >> 4;
    const int blk  = blockIdx.x;
    const int nsteps = *stepsp;
    const float scale = dt_scale[0] * 0.01f;
    const int n0 = 32 * w;            // this wave's 32 output features (L1/L2)

    // ---- weight fragments: W1 bf16 (A[m=ln][k=32ks+8q+j]); W2/W3 fp8
    //      (A[m=ln][k=128kk+32q+j], 32 contiguous bytes per lane) ----
    v8s w1f[2][2];
    v8i w2f[2][2], w3f[2];
    #pragma unroll
    for (int t = 0; t < 2; t++)
        #pragma unroll
        for (int ks = 0; ks < 2; ks++)
            w1f[t][ks] = *(const v8s*)(W1t + (n0 + 16 * t + ln) * 64 + 32 * ks + 8 * q);
    #pragma unroll
    for (int t = 0; t < 2; t++)
        #pragma unroll
        for (int kk = 0; kk < 2; kk++)
            w2f[t][kk] = *(const v8i*)(W2q + (n0 + 16 * t + ln) * 256 + 128 * kk + 32 * q);
    if (w < 4) {
        #pragma unroll
        for (int kk = 0; kk < 2; kk++)
            w3f[kk] = *(const v8i*)(W3q + (16 * w + ln) * 256 + 128 * kk + 32 * q);
    }
    // ---- biases (C rows = feats 4q+i); b1/b2 pre-scaled by 2/ln2 ----
    v4f b1v[2], b2v[2], b3v = {0.f, 0.f, 0.f, 0.f};
    #pragma unroll
    for (int t = 0; t < 2; t++) {
        b1v[t] = *(const v4f*)(b1 + n0 + 16 * t + 4 * q) * LOG2E2;
        b2v[t] = *(const v4f*)(b2 + n0 + 16 * t + 4 * q) * LOG2E2;
    }
    if (w < 4) b3v = *(const v4f*)(b3 + 16 * w + 4 * q);

    // ---- x state in registers of waves 0-3: feats 16w+4q+i, batch ln ----
    v4f x = {0.f, 0.f, 0.f, 0.f};
    unsigned tbase = 0;
    const int xw0 = ln * XPITCH + 16 * w + 4 * q;
    if (w < 4) {
        x = *(const v4f*)(x0 + (size_t)(blk * TILE_M + ln) * STATE_DIM + 16 * w + 4 * q);
        uint2 p; p.x = pk2bf(x[0], x[1]); p.y = pk2bf(x[2], x[3]);
        *(uint2*)(xb + xw0) = p;
        tbase = (unsigned)(blk * TILE_M + ln) * (unsigned)((nsteps + 1) * STATE_DIM)
              + 16 * w + 4 * q;
        *(v4f*)(out + tbase) = x;          // trajectory sample 0
        tbase += STATE_DIM;
    }
    __syncthreads();

    // ---- hoisted LDS indices ----
    int xrd[2];
    #pragma unroll
    for (int ks = 0; ks < 2; ks++) xrd[ks] = ln * XPITCH + 32 * ks + 8 * q;
    const int hq0 = ln * HQPITCH + 32 * q;        // fp8 B-frag read base (+128*kk)
    const int hwq = ln * HQPITCH + n0 + 4 * q;    // fp8 write base (+16 for tile 1)

    for (int s = 0; s < nsteps; s++) {
        // ---- L1 (bf16): h1 = tanh(x @ W1s + b1s), stored as fp8 x16 ----
        v8s xa0 = *(const v8s*)(xb + xrd[0]);
        v8s xa1 = *(const v8s*)(xb + xrd[1]);
        v4f a0 = b1v[0], a1 = b1v[1];
        a0 = __builtin_amdgcn_mfma_f32_16x16x32_bf16(w1f[0][0], xa0, a0, 0, 0, 0);
        a1 = __builtin_amdgcn_mfma_f32_16x16x32_bf16(w1f[1][0], xa0, a1, 0, 0, 0);
        a0 = __builtin_amdgcn_mfma_f32_16x16x32_bf16(w1f[0][1], xa1, a0, 0, 0, 0);
        a1 = __builtin_amdgcn_mfma_f32_16x16x32_bf16(w1f[1][1], xa1, a1, 0, 0, 0);
        {
            int p0 = __builtin_amdgcn_cvt_pk_fp8_f32(fast_tanh16(a0[0]), fast_tanh16(a0[1]), 0, false);
            p0     = __builtin_amdgcn_cvt_pk_fp8_f32(fast_tanh16(a0[2]), fast_tanh16(a0[3]), p0, true);
            int p1 = __builtin_amdgcn_cvt_pk_fp8_f32(fast_tanh16(a1[0]), fast_tanh16(a1[1]), 0, false);
            p1     = __builtin_amdgcn_cvt_pk_fp8_f32(fast_tanh16(a1[2]), fast_tanh16(a1[3]), p1, true);
            *(int*)(h1b + hwq)      = p0;
            *(int*)(h1b + hwq + 16) = p1;
        }
        sync_lds();

        // ---- L2 (MX fp8 K=128): h2 = tanh(h1 @ W2s + b2s) ----
        v8i hb0 = *(const v8i*)(h1b + hq0);
        v8i hb1 = *(const v8i*)(h1b + hq0 + 128);
        a0 = b2v[0]; a1 = b2v[1];
        a0 = __builtin_amdgcn_mfma_scale_f32_16x16x128_f8f6f4(w2f[0][0], hb0, a0, 0, 0, 0, SCALE_A, 0, SCALE_B);
        a1 = __builtin_amdgcn_mfma_scale_f32_16x16x128_f8f6f4(w2f[1][0], hb0, a1, 0, 0, 0, SCALE_A, 0, SCALE_B);
        a0 = __builtin_amdgcn_mfma_scale_f32_16x16x128_f8f6f4(w2f[0][1], hb1, a0, 0, 0, 0, SCALE_A, 0, SCALE_B);
        a1 = __builtin_amdgcn_mfma_scale_f32_16x16x128_f8f6f4(w2f[1][1], hb1, a1, 0, 0, 0, SCALE_A, 0, SCALE_B);
        {
            int p0 = __builtin_amdgcn_cvt_pk_fp8_f32(fast_tanh16(a0[0]), fast_tanh16(a0[1]), 0, false);
            p0     = __builtin_amdgcn_cvt_pk_fp8_f32(fast_tanh16(a0[2]), fast_tanh16(a0[3]), p0, true);
            int p1 = __builtin_amdgcn_cvt_pk_fp8_f32(fast_tanh16(a1[0]), fast_tanh16(a1[1]), 0, false);
            p1     = __builtin_amdgcn_cvt_pk_fp8_f32(fast_tanh16(a1[2]), fast_tanh16(a1[3]), p1, true);
            *(int*)(h2b + hwq)      = p0;
            *(int*)(h2b + hwq + 16) = p1;
        }
        sync_lds();

        // ---- L3 (MX fp8 K=128) + Euler + trajectory (waves 0-3) ----
        if (w < 4) {
            v8i hc0 = *(const v8i*)(h2b + hq0);
            v8i hc1 = *(const v8i*)(h2b + hq0 + 128);
            v4f a3 = b3v;
            a3 = __builtin_amdgcn_mfma_scale_f32_16x16x128_f8f6f4(w3f[0], hc0, a3, 0, 0, 0, SCALE_A, 0, SCALE_B);
            a3 = __builtin_amdgcn_mfma_scale_f32_16x16x128_f8f6f4(w3f[1], hc1, a3, 0, 0, 0, SCALE_A, 0, SCALE_B);
            #pragma unroll
            for (int i = 0; i < 4; i++)
                x[i] = fmaf(a3[i], scale, x[i]);
            uint2 p; p.x = pk2bf(x[0], x[1]); p.y = pk2bf(x[2], x[3]);
            *(uint2*)(xb + xw0) = p;
            *(v4f*)(out + tbase) = x;      // trajectory sample s+1 (floats free)
            tbase += STATE_DIM;
        }
        sync_lds();
    }
}

extern "C" void kernel_launch(void* const* d_in, const int* in_sizes, int n_in,
                              void* d_out, int out_size, void* d_ws, size_t ws_size,
                              hipStream_t stream) {
    const float* x0 = (const float*)d_in[0];
    const float* W1 = (const float*)d_in[1];
    const float* b1 = (const float*)d_in[2];
    const float* W2 = (const float*)d_in[3];
    const float* b2 = (const float*)d_in[4];
    const float* W3 = (const float*)d_in[5];
    const float* b3 = (const float*)d_in[6];
    const float* dt = (const float*)d_in[7];
    const int* steps = (const int*)d_in[8];

    short* W1t = (short*)d_ws;                        // 16384 bf16 (scaled)
    unsigned char* W2q = (unsigned char*)(W1t + 16384);  // 65536 fp8 (scaled x64)
    unsigned char* W3q = W2q + 65536;                    // 16384 fp8 (x64)

    prep_weights<<<384, 256, 0, stream>>>(W1, W2, W3, W1t, W2q, W3q);
    ode_kernel<<<NBLK, 512, 0, stream>>>(x0, b1, b2, b3, dt, steps,
                                         W1t, W2q, W3q, (float*)d_out);
}